// Round 1
// baseline (648.201 us; speedup 1.0000x reference)
//
#include <hip/hip_runtime.h>

// ---- problem constants (fixed shapes from the reference) ----
constexpr int B_    = 64;
constexpr int NPG_  = 512;
constexpr int DEG_  = 16;
constexpr int D_    = 128;
constexpr int H_    = 4;
constexpr int K_    = 5;
constexpr int NHID_ = 50;
constexpr int CB_   = 512;
constexpr int N_    = B_ * NPG_;   // 32768
constexpr int E_    = N_ * DEG_;   // 524288
constexpr float BN_SCALE_ = 0.99999500003749969f;  // 1/sqrt(1+1e-5)
constexpr float EPS_ = 1e-6f;

// =================== CSR build ===================
__global__ void k_zero(int* p, int n) {
    int i = blockIdx.x * 256 + threadIdx.x;
    if (i < n) p[i] = 0;
}

__global__ void k_count(const int* __restrict__ dst, int* __restrict__ counts) {
    int e = blockIdx.x * 256 + threadIdx.x;
    if (e < E_) atomicAdd(&counts[dst[e]], 1);
}

// single block, 1024 threads, 32 elements each -> exclusive scan of counts[N]
__global__ __launch_bounds__(1024) void k_scan(const int* __restrict__ counts,
                                               int* __restrict__ rowptr,
                                               int* __restrict__ woff) {
    __shared__ int lsums[1024];
    int t = threadIdx.x;
    int base = t * 32;
    int local[32];
    int s = 0;
    for (int i = 0; i < 32; i++) { local[i] = counts[base + i]; s += local[i]; }
    lsums[t] = s;
    __syncthreads();
    for (int off = 1; off < 1024; off <<= 1) {
        int v = lsums[t];
        int add = (t >= off) ? lsums[t - off] : 0;
        __syncthreads();
        lsums[t] = v + add;
        __syncthreads();
    }
    int excl = lsums[t] - s;   // exclusive prefix for this chunk
    for (int i = 0; i < 32; i++) {
        rowptr[base + i] = excl;
        woff[base + i]   = excl;
        excl += local[i];
    }
    if (t == 1023) rowptr[N_] = excl;
}

__global__ void k_fill(const int* __restrict__ src, const int* __restrict__ dst,
                       int* __restrict__ woff, int* __restrict__ col) {
    int e = blockIdx.x * 256 + threadIdx.x;
    if (e < E_) {
        int d = dst[e];
        int p = atomicAdd(&woff[d], 1);
        col[p] = src[e];
    }
}

// =================== embedding ===================
__global__ void k_embed(const int* __restrict__ x, const float* __restrict__ emb,
                        float* __restrict__ h) {
    int i = blockIdx.x * 256 + threadIdx.x;   // over N*D
    int node = i >> 7, f = i & 127;
    h[i] = emb[x[node] * D_ + f];
}

// =================== GIN aggregation: z = h + sum_{j->i} h_j ===================
// one wave (64 lanes) per node; lane covers features f and f+64
__global__ void k_agg(const float* __restrict__ h, const int* __restrict__ rowptr,
                      const int* __restrict__ col, float* __restrict__ z) {
    int wave = threadIdx.x >> 6;
    int lane = threadIdx.x & 63;
    int node = blockIdx.x * 4 + wave;
    int beg = rowptr[node], end = rowptr[node + 1];
    float a0 = h[node * D_ + lane];
    float a1 = h[node * D_ + lane + 64];
    for (int e = beg; e < end; e++) {
        int c = col[e];
        a0 += h[c * D_ + lane];
        a1 += h[c * D_ + lane + 64];
    }
    z[node * D_ + lane]      = a0;
    z[node * D_ + lane + 64] = a1;
}

// =================== GIN MLP: h = BN(relu(z@W1+b1)@W2+b2) [+relu] ===================
// 256 threads, 64 rows per block. LDS: z tile [64][128] then hidden [64][256].
__global__ __launch_bounds__(256) void k_gin_mlp(
    const float* __restrict__ z,
    const float* __restrict__ W1, const float* __restrict__ b1,
    const float* __restrict__ W2, const float* __restrict__ b2,
    const float* __restrict__ gamma, const float* __restrict__ beta,
    int relu_out, float* __restrict__ h) {
    __shared__ float lds[64 * 256];   // 64 KB
    int t = threadIdx.x;
    int rowBase = blockIdx.x * 64;
    // phase 1: load z tile [64][128] coalesced
    #pragma unroll
    for (int i = 0; i < 32; i++) {
        int idx = t + i * 256;
        lds[idx] = z[rowBase * D_ + idx];
    }
    __syncthreads();
    int tx = t & 63, ty = t >> 6;
    int r0 = ty * 16;
    // phase 2: hidden = z @ W1 + b1  (thread: 16 rows x 4 hidden cols)
    float acc[16][4];
    {
        float bb0 = b1[tx], bb1 = b1[tx + 64], bb2 = b1[tx + 128], bb3 = b1[tx + 192];
        #pragma unroll
        for (int r = 0; r < 16; r++) { acc[r][0]=bb0; acc[r][1]=bb1; acc[r][2]=bb2; acc[r][3]=bb3; }
    }
    for (int k = 0; k < 128; k += 4) {
        float w[4][4];
        #pragma unroll
        for (int kk = 0; kk < 4; kk++)
            #pragma unroll
            for (int j = 0; j < 4; j++)
                w[kk][j] = W1[(k + kk) * 256 + tx + j * 64];
        #pragma unroll
        for (int r = 0; r < 16; r++) {
            float4 zv = *(const float4*)&lds[(r0 + r) * 128 + k];
            #pragma unroll
            for (int j = 0; j < 4; j++) {
                acc[r][j] = fmaf(zv.x, w[0][j], acc[r][j]);
                acc[r][j] = fmaf(zv.y, w[1][j], acc[r][j]);
                acc[r][j] = fmaf(zv.z, w[2][j], acc[r][j]);
                acc[r][j] = fmaf(zv.w, w[3][j], acc[r][j]);
            }
        }
    }
    __syncthreads();   // all zt reads done
    // phase 3: relu -> LDS hidden [64][256]
    #pragma unroll
    for (int r = 0; r < 16; r++)
        #pragma unroll
        for (int j = 0; j < 4; j++)
            lds[(r0 + r) * 256 + tx + j * 64] = fmaxf(acc[r][j], 0.f);
    __syncthreads();
    // phase 4: out = hidden @ W2 + b2 (thread: 16 rows x 2 out cols)
    float acc2[16][2];
    {
        float bb0 = b2[tx], bb1 = b2[tx + 64];
        #pragma unroll
        for (int r = 0; r < 16; r++) { acc2[r][0] = bb0; acc2[r][1] = bb1; }
    }
    for (int c = 0; c < 256; c += 4) {
        float w0[4], w1[4];
        #pragma unroll
        for (int cc = 0; cc < 4; cc++) {
            w0[cc] = W2[(c + cc) * 128 + tx];
            w1[cc] = W2[(c + cc) * 128 + tx + 64];
        }
        #pragma unroll
        for (int r = 0; r < 16; r++) {
            float4 hv = *(const float4*)&lds[(r0 + r) * 256 + c];
            acc2[r][0] = fmaf(hv.x, w0[0], acc2[r][0]);
            acc2[r][0] = fmaf(hv.y, w0[1], acc2[r][0]);
            acc2[r][0] = fmaf(hv.z, w0[2], acc2[r][0]);
            acc2[r][0] = fmaf(hv.w, w0[3], acc2[r][0]);
            acc2[r][1] = fmaf(hv.x, w1[0], acc2[r][1]);
            acc2[r][1] = fmaf(hv.y, w1[1], acc2[r][1]);
            acc2[r][1] = fmaf(hv.z, w1[2], acc2[r][1]);
            acc2[r][1] = fmaf(hv.w, w1[3], acc2[r][1]);
        }
    }
    // epilogue: eval BN + optional relu
    float g0 = BN_SCALE_ * gamma[tx],      g1 = BN_SCALE_ * gamma[tx + 64];
    float be0 = beta[tx],                  be1 = beta[tx + 64];
    #pragma unroll
    for (int r = 0; r < 16; r++) {
        float v0 = fmaf(acc2[r][0], g0, be0);
        float v1 = fmaf(acc2[r][1], g1, be1);
        if (relu_out) { v0 = fmaxf(v0, 0.f); v1 = fmaxf(v1, 0.f); }
        h[(rowBase + r0 + r) * D_ + tx]      = v0;
        h[(rowBase + r0 + r) * D_ + tx + 64] = v1;
    }
}

// =================== partitioner: S = softmax(relu(h@W1+b1)@W2+b2) ===================
__global__ __launch_bounds__(256) void k_part(
    const float* __restrict__ h,
    const float* __restrict__ W1, const float* __restrict__ b1,
    const float* __restrict__ W2, const float* __restrict__ b2,
    float* __restrict__ S) {
    __shared__ float zt[64 * 128];   // 32 KB
    __shared__ float ht[64 * 52];
    __shared__ float lt[64 * 5];
    int t = threadIdx.x;
    int base = blockIdx.x * 64;
    #pragma unroll
    for (int i = 0; i < 32; i++) { int idx = t + i * 256; zt[idx] = h[base * D_ + idx]; }
    __syncthreads();
    int tx = t & 63, ty = t >> 6, r0 = ty * 16;
    if (tx < NHID_) {
        float acc[16];
        float bb = b1[tx];
        #pragma unroll
        for (int r = 0; r < 16; r++) acc[r] = bb;
        for (int k = 0; k < 128; k++) {
            float w = W1[k * NHID_ + tx];
            #pragma unroll
            for (int r = 0; r < 16; r++) acc[r] = fmaf(zt[(r0 + r) * 128 + k], w, acc[r]);
        }
        #pragma unroll
        for (int r = 0; r < 16; r++) ht[(r0 + r) * 52 + tx] = fmaxf(acc[r], 0.f);
    }
    __syncthreads();
    if (tx < K_) {
        float acc[16];
        float bb = b2[tx];
        #pragma unroll
        for (int r = 0; r < 16; r++) acc[r] = bb;
        for (int c = 0; c < NHID_; c++) {
            float w = W2[c * K_ + tx];
            #pragma unroll
            for (int r = 0; r < 16; r++) acc[r] = fmaf(ht[(r0 + r) * 52 + c], w, acc[r]);
        }
        #pragma unroll
        for (int r = 0; r < 16; r++) lt[(r0 + r) * 5 + tx] = acc[r];
    }
    __syncthreads();
    if (t < 64) {
        float l0 = lt[t*5], l1 = lt[t*5+1], l2 = lt[t*5+2], l3 = lt[t*5+3], l4 = lt[t*5+4];
        float m = fmaxf(fmaxf(fmaxf(l0, l1), fmaxf(l2, l3)), l4);
        float e0 = expf(l0 - m), e1 = expf(l1 - m), e2 = expf(l2 - m),
              e3 = expf(l3 - m), e4 = expf(l4 - m);
        float inv = 1.0f / (e0 + e1 + e2 + e3 + e4);
        int node = base + t;
        S[node*5]   = e0*inv; S[node*5+1] = e1*inv; S[node*5+2] = e2*inv;
        S[node*5+3] = e3*inv; S[node*5+4] = e4*inv;
    }
}

// =================== cf (soft cluster means) + residue (graph mean pool) ===================
__global__ void k_cf(const float* __restrict__ h, const float* __restrict__ S,
                     float* __restrict__ cf, float* __restrict__ residue) {
    int g = blockIdx.x;      // graph
    int d = threadIdx.x;     // 128 threads, one feature each
    float acc[5] = {0, 0, 0, 0, 0};
    float ssum[5] = {0, 0, 0, 0, 0};
    float rs = 0;
    const float* hg = h + (size_t)g * NPG_ * D_;
    const float* Sg = S + (size_t)g * NPG_ * K_;
    for (int n = 0; n < NPG_; n++) {
        float hv = hg[n * D_ + d];
        rs += hv;
        #pragma unroll
        for (int k = 0; k < 5; k++) {
            float sv = Sg[n * 5 + k];
            acc[k] = fmaf(sv, hv, acc[k]);
            ssum[k] += sv;
        }
    }
    #pragma unroll
    for (int k = 0; k < 5; k++)
        cf[((size_t)g * K_ + k) * D_ + d] = acc[k] / (ssum[k] + EPS_);
    residue[g * D_ + d] = rs * (1.0f / NPG_);
}

// =================== VQ: zq = codebook[argmin ||cf - cb||^2] ===================
__global__ __launch_bounds__(256) void k_vq(const float* __restrict__ cf,
                                            const float* __restrict__ cb,
                                            float* __restrict__ zq) {
    __shared__ float row[128];
    __shared__ float bd[256];
    __shared__ int bi[256];
    int r = blockIdx.x;   // 0..B*K-1
    int t = threadIdx.x;
    if (t < 128) row[t] = cf[r * 128 + t];
    __syncthreads();
    float best = 1e30f; int bidx = 0;
    for (int j = t; j < CB_; j += 256) {
        float d2 = 0;
        const float* cbr = cb + j * 128;
        #pragma unroll 8
        for (int d = 0; d < 128; d++) {
            float diff = row[d] - cbr[d];
            d2 = fmaf(diff, diff, d2);
        }
        if (d2 < best) { best = d2; bidx = j; }
    }
    bd[t] = best; bi[t] = bidx;
    __syncthreads();
    for (int s = 128; s > 0; s >>= 1) {
        if (t < s) {
            if (bd[t + s] < bd[t] || (bd[t + s] == bd[t] && bi[t + s] < bi[t])) {
                bd[t] = bd[t + s]; bi[t] = bi[t + s];
            }
        }
        __syncthreads();
    }
    int idx = bi[0];
    if (t < 128) zq[r * 128 + t] = cb[idx * 128 + t];
}

// =================== attention + gate + classifier, block per graph ===================
__global__ __launch_bounds__(128) void k_head(
    const float* __restrict__ residue, const float* __restrict__ zq,
    const float* __restrict__ Wq, const float* __restrict__ Wk,
    const float* __restrict__ Wv, const float* __restrict__ Wo,
    const float* __restrict__ gW1, const float* __restrict__ gb1,
    const float* __restrict__ gW2, const float* __restrict__ gb2,
    const float* __restrict__ cW1, const float* __restrict__ cb1,
    const float* __restrict__ cW2, const float* __restrict__ cb2,
    const float* __restrict__ cW3, const float* __restrict__ cb3,
    float* __restrict__ out) {
    __shared__ float res[128], zqs[5 * 128], q[128], kk[5 * 128], vv[5 * 128];
    __shared__ float aw[4 * 5];
    __shared__ float att[128], attO[128], fused[128];
    __shared__ float g1h[64];
    __shared__ float z1[512], z2[256];
    int b = blockIdx.x, t = threadIdx.x;
    res[t] = residue[b * 128 + t];
    #pragma unroll
    for (int j = 0; j < 5; j++) zqs[j * 128 + t] = zq[(b * 5 + j) * 128 + t];
    __syncthreads();
    // q = residue @ Wq
    {
        float a = 0;
        for (int k = 0; k < 128; k++) a = fmaf(res[k], Wq[k * 128 + t], a);
        q[t] = a;
    }
    // k,v = zq @ Wk / Wv
    {
        float ak[5] = {0,0,0,0,0}, av[5] = {0,0,0,0,0};
        for (int k = 0; k < 128; k++) {
            float wk = Wk[k * 128 + t], wv = Wv[k * 128 + t];
            #pragma unroll
            for (int j = 0; j < 5; j++) {
                float zv = zqs[j * 128 + k];
                ak[j] = fmaf(zv, wk, ak[j]);
                av[j] = fmaf(zv, wv, av[j]);
            }
        }
        #pragma unroll
        for (int j = 0; j < 5; j++) { kk[j * 128 + t] = ak[j]; vv[j * 128 + t] = av[j]; }
    }
    __syncthreads();
    // scores per (head, cluster)
    if (t < 20) {
        int hh = t / 5, j = t % 5;
        float s = 0;
        for (int d = 0; d < 32; d++) s = fmaf(q[hh * 32 + d], kk[j * 128 + hh * 32 + d], s);
        aw[hh * 5 + j] = s * 0.17677669529663687f;   // 1/sqrt(32)
    }
    __syncthreads();
    if (t < 4) {
        float m = -1e30f;
        for (int j = 0; j < 5; j++) m = fmaxf(m, aw[t * 5 + j]);
        float e[5], sum = 0;
        for (int j = 0; j < 5; j++) { e[j] = expf(aw[t * 5 + j] - m); sum += e[j]; }
        for (int j = 0; j < 5; j++) aw[t * 5 + j] = e[j] / sum;
    }
    __syncthreads();
    // att (pre-Wo)
    {
        int hh = t >> 5;
        float a = 0;
        #pragma unroll
        for (int j = 0; j < 5; j++) a = fmaf(aw[hh * 5 + j], vv[j * 128 + t], a);
        att[t] = a;
    }
    __syncthreads();
    // attO = att @ Wo
    {
        float a = 0;
        for (int k = 0; k < 128; k++) a = fmaf(att[k], Wo[k * 128 + t], a);
        attO[t] = a;
    }
    __syncthreads();
    // gate hidden: relu([res, attO] @ gW1 + gb1) -> [64]
    if (t < 64) {
        float a = gb1[t];
        for (int k = 0; k < 128; k++) a = fmaf(res[k],  gW1[k * 64 + t], a);
        for (int k = 0; k < 128; k++) a = fmaf(attO[k], gW1[(128 + k) * 64 + t], a);
        g1h[t] = fmaxf(a, 0.f);
    }
    __syncthreads();
    // gate output + fuse
    {
        float a = gb2[t];
        for (int c = 0; c < 64; c++) a = fmaf(g1h[c], gW2[c * 128 + t], a);
        float g = 1.0f / (1.0f + expf(-a));
        fused[t] = g * res[t] + (1.0f - g) * attO[t];
    }
    __syncthreads();
    // classifier
    #pragma unroll
    for (int j = 0; j < 4; j++) {
        int c = t + j * 128;
        float a = cb1[c];
        for (int k = 0; k < 128; k++) a = fmaf(fused[k], cW1[k * 512 + c], a);
        z1[c] = fmaxf(a, 0.f);
    }
    __syncthreads();
    #pragma unroll
    for (int j = 0; j < 2; j++) {
        int c = t + j * 128;
        float a = cb2[c];
        for (int k = 0; k < 512; k++) a = fmaf(z1[k], cW2[k * 256 + c], a);
        z2[c] = fmaxf(a, 0.f);
    }
    __syncthreads();
    if (t < 2) {
        float a = cb3[t];
        for (int k = 0; k < 256; k++) a = fmaf(z2[k], cW3[k * 2 + t], a);
        out[b * 2 + t] = a;
    }
}

// =================== launch ===================
extern "C" void kernel_launch(void* const* d_in, const int* in_sizes, int n_in,
                              void* d_out, int out_size, void* d_ws, size_t ws_size,
                              hipStream_t stream) {
    const int*   x          = (const int*)d_in[0];
    const int*   edge_index = (const int*)d_in[1];   // [2][E]: src then dst
    // d_in[2] = batch (node i -> graph i/NPG by construction; unused)
    const float* emb      = (const float*)d_in[3];
    const float* gin_W1   = (const float*)d_in[4];
    const float* gin_b1   = (const float*)d_in[5];
    const float* gin_W2   = (const float*)d_in[6];
    const float* gin_b2   = (const float*)d_in[7];
    const float* bn_gamma = (const float*)d_in[8];
    const float* bn_beta  = (const float*)d_in[9];
    const float* part_W1  = (const float*)d_in[10];
    const float* part_b1  = (const float*)d_in[11];
    const float* part_W2  = (const float*)d_in[12];
    const float* part_b2  = (const float*)d_in[13];
    const float* Wq       = (const float*)d_in[14];
    const float* Wk       = (const float*)d_in[15];
    const float* Wv       = (const float*)d_in[16];
    const float* Wo       = (const float*)d_in[17];
    const float* gate_W1  = (const float*)d_in[18];
    const float* gate_b1  = (const float*)d_in[19];
    const float* gate_W2  = (const float*)d_in[20];
    const float* gate_b2  = (const float*)d_in[21];
    const float* codebook = (const float*)d_in[22];
    const float* cls_W1   = (const float*)d_in[23];
    const float* cls_b1   = (const float*)d_in[24];
    const float* cls_W2   = (const float*)d_in[25];
    const float* cls_b2   = (const float*)d_in[26];
    const float* cls_W3   = (const float*)d_in[27];
    const float* cls_b3   = (const float*)d_in[28];

    const int* srcp = edge_index;
    const int* dstp = edge_index + E_;

    // workspace carve-up
    char* w = (char*)d_ws;
    float* h  = (float*)w;  w += (size_t)N_ * D_ * 4;
    float* z  = (float*)w;  w += (size_t)N_ * D_ * 4;
    float* S  = (float*)w;  w += (size_t)N_ * K_ * 4;
    float* cf = (float*)w;  w += (size_t)B_ * K_ * D_ * 4;
    float* zq = (float*)w;  w += (size_t)B_ * K_ * D_ * 4;
    float* residue = (float*)w;  w += (size_t)B_ * D_ * 4;
    int* counts = (int*)w;  w += (size_t)N_ * 4;
    int* rowptr = (int*)w;  w += (size_t)(N_ + 4) * 4;
    int* woff   = (int*)w;  w += (size_t)N_ * 4;
    int* col    = (int*)w;  w += (size_t)E_ * 4;

    // ---- CSR build for segment_sum over dst ----
    k_zero <<<(N_ + 255) / 256, 256, 0, stream>>>(counts, N_);
    k_count<<<E_ / 256, 256, 0, stream>>>(dstp, counts);
    k_scan <<<1, 1024, 0, stream>>>(counts, rowptr, woff);
    k_fill <<<E_ / 256, 256, 0, stream>>>(srcp, dstp, woff, col);

    // ---- embedding ----
    k_embed<<<N_ * D_ / 256, 256, 0, stream>>>(x, emb, h);

    // ---- GIN layers ----
    for (int l = 0; l < 3; l++) {
        k_agg<<<N_ / 4, 256, 0, stream>>>(h, rowptr, col, z);
        k_gin_mlp<<<N_ / 64, 256, 0, stream>>>(
            z,
            gin_W1 + (size_t)l * D_ * 2 * D_, gin_b1 + (size_t)l * 2 * D_,
            gin_W2 + (size_t)l * 2 * D_ * D_, gin_b2 + (size_t)l * D_,
            bn_gamma + (size_t)l * D_, bn_beta + (size_t)l * D_,
            (l < 2) ? 1 : 0, h);
    }

    // ---- partitioner softmax assignments ----
    k_part<<<N_ / 64, 256, 0, stream>>>(h, part_W1, part_b1, part_W2, part_b2, S);

    // ---- cluster features + residue pooling ----
    k_cf<<<B_, 128, 0, stream>>>(h, S, cf, residue);

    // ---- VQ nearest codebook ----
    k_vq<<<B_ * K_, 256, 0, stream>>>(cf, codebook, zq);

    // ---- attention + gate + classifier ----
    k_head<<<B_, 128, 0, stream>>>(residue, zq, Wq, Wk, Wv, Wo,
                                   gate_W1, gate_b1, gate_W2, gate_b2,
                                   cls_W1, cls_b1, cls_W2, cls_b2, cls_W3, cls_b3,
                                   (float*)d_out);
}